// Round 9
// baseline (160.008 us; speedup 1.0000x reference)
//
#include <hip/hip_runtime.h>
#include <hip/hip_bf16.h>

// GAT layer: B=2, N=2048, C_IN=128, H=16, c=8.
// E(i,j) = exp(lrelu(lp_i+lc_j))*2^-12 = max(P1_i*Q1_j, P2_i*Q2_j)*adj  (f16,
// scale cancels in softmax). Aggregation via mfma_f32_16x16x32_f16 with
// B = [h feats | ones | zeros] -> out + lsum in one accumulator.
// Round 9: conflict-free LDS (D = ch*64+lane, lane-linear b128 read+write),
// 2-deep pipelined Q/H prefetch, adj copy in its own streaming kernel.
// d_out = [out: B*N*128][adj copy: B*N*N]

#define B_   2
#define N_   2048
#define CIN_ 128
#define H_   16

typedef _Float16 h2  __attribute__((ext_vector_type(2)));
typedef _Float16 v8h __attribute__((ext_vector_type(8)));
typedef float    v4f __attribute__((ext_vector_type(4)));

#define SC6 0.015625f   // 2^-6

__device__ inline h2 pk_f16(float a, float b) {
  return __builtin_bit_cast(h2, __builtin_amdgcn_cvt_pkrtz(a, b));
}
__device__ inline unsigned as_u32(h2 v) { return __builtin_bit_cast(unsigned, v); }
__device__ inline h2 as_h2(unsigned u) { return __builtin_bit_cast(h2, u); }

__global__ __launch_bounds__(128) void proj_kernel(
    const float* __restrict__ nf, const float* __restrict__ W,
    const float* __restrict__ bias, const float* __restrict__ a,
    unsigned* __restrict__ hQ, unsigned* __restrict__ lq1,
    unsigned* __restrict__ lq2, float* __restrict__ lpT) {
  const int row0 = blockIdx.x * 2;       // 2 consecutive rows (same batch)
  const int t    = threadIdx.x;          // output column 0..127
  __shared__ float sNf[2][CIN_];
  if (t < 64) {
    ((float4*)&sNf[0][0])[t] = ((const float4*)(nf + (long)row0 * CIN_))[t];
  }
  __syncthreads();
  float acc0 = bias[t], acc1 = acc0;
#pragma unroll 16
  for (int k = 0; k < CIN_; ++k) {
    const float w = W[k * 128 + t];
    acc0 = fmaf(sNf[0][k], w, acc0);
    acc1 = fmaf(sNf[1][k], w, acc1);
  }
  const int h = t >> 3, kc = t & 7;
  const int b = row0 >> 11, n0 = row0 & (N_ - 1);
  const int bh = b * H_ + h;
  const int cdw = n0 >> 1;               // j-pair dword index
  // hQ: feat-major f16 [bh][feat 0..15][j-pair]; feats 8..15 = ones/zeros
  hQ[(bh * 16 + kc) * (N_ / 2) + cdw] = as_u32(pk_f16(acc0, acc1));
#pragma unroll
  for (int i2 = 0; i2 < 2; ++i2) {       // fill feats 8..15 for all 32 bh
    const int u = t * 2 + i2;
    const int bh2 = u >> 3, f = 8 + (u & 7);
    hQ[(bh2 * 16 + f) * (N_ / 2) + cdw] = (f == 8) ? 0x3C003C00u : 0u;
  }
  const float ap = a[h * 16 + kc], ac = a[h * 16 + 8 + kc];
  float accr[2] = {acc0, acc1};
  float q1v[2], q2v[2], lpv2[2];
#pragma unroll
  for (int r = 0; r < 2; ++r) {
    float lpv = accr[r] * ap, lcv = accr[r] * ac;
#pragma unroll
    for (int s = 1; s < 8; s <<= 1) {
      lpv += __shfl_xor(lpv, s);
      lcv += __shfl_xor(lcv, s);
    }
    lpv2[r] = lpv;
    q1v[r] = __expf(lcv) * SC6;
    q2v[r] = __expf(0.2f * lcv) * SC6;
  }
  if (kc == 0) {
    lpT[bh * N_ + n0]     = lpv2[0];
    lpT[bh * N_ + n0 + 1] = lpv2[1];
    lq1[bh * (N_ / 2) + cdw] = as_u32(pk_f16(q1v[0], q1v[1]));
    lq2[bh * (N_ / 2) + cdw] = as_u32(pk_f16(q2v[0], q2v[1]));
  }
}

// Pure streaming copy of the adjacency to d_out (second tuple element).
__global__ __launch_bounds__(256) void adjcopy_kernel(
    const float4* __restrict__ src, float4* __restrict__ dst) {
  const int i = blockIdx.x * 1024 + threadIdx.x;
#pragma unroll
  for (int s = 0; s < 4; ++s) dst[i + s * 256] = src[i + s * 256];
}

__global__ __launch_bounds__(512) void attn_kernel(
    const float* __restrict__ adj, const unsigned* __restrict__ hQ,
    const unsigned* __restrict__ lq1, const unsigned* __restrict__ lq2,
    const float* __restrict__ lpT, float* __restrict__ out) {
  const int hgroup = blockIdx.x & 1;
  const int rest   = blockIdx.x >> 1;
  const int b      = rest >> 7;          // 128 i-tiles per batch
  const int i0     = (rest & 127) * 16;
  const int tid    = threadIdx.x;
  const int w      = tid >> 6;           // 0..7 (wave = head)
  const int lane   = tid & 63;

  // f16 adjacency tile, 16-B units D = ch*64 + q*16 + m  (lane-linear reads)
  __shared__ uint4 sA[4096];             // 64 KB

  // Stage: thread handles dest unit D = s*512+tid; source = row m, 8 cols.
  {
    const float* abase = adj + (long)(b * N_ + i0) * N_;
#pragma unroll
    for (int s = 0; s < 8; ++s) {
      const int D = s * 512 + tid;
      const int m = D & 15, qc = D >> 4;           // qc = ch*4+q
      const int c0 = (qc >> 2) * 32 + (qc & 3) * 8;
      const float4 fa = *(const float4*)(abase + m * N_ + c0);
      const float4 fb = *(const float4*)(abase + m * N_ + c0 + 4);
      sA[D] = (uint4){as_u32(pk_f16(fa.x, fa.y)), as_u32(pk_f16(fa.z, fa.w)),
                      as_u32(pk_f16(fb.x, fb.y)), as_u32(pk_f16(fb.z, fb.w))};
    }
  }
  __syncthreads();

  const int hw = hgroup * 8 + w;
  const int bh = b * H_ + hw;
  const int m  = lane & 15;              // A row / B col / D col
  const int q  = lane >> 4;              // k-quad

  const float lp = lpT[bh * N_ + i0 + m];
  const float p1 = __expf(lp) * SC6, p2 = __expf(0.2f * lp) * SC6;
  const h2 P1 = pk_f16(p1, p1), P2 = pk_f16(p2, p2);

  const unsigned* q1p = lq1 + bh * (N_ / 2) + q * 4;
  const unsigned* q2p = lq2 + bh * (N_ / 2) + q * 4;
  const unsigned* hp  = hQ + (bh * 16 + m) * (N_ / 2) + q * 4;

  v4f acc = {0.0f, 0.0f, 0.0f, 0.0f};

  // 2-deep pipelined loads over 64 chunks (16 dwords per chunk stride).
  uint4 q1A = *(const uint4*)(q1p), q2A = *(const uint4*)(q2p),
        hA  = *(const uint4*)(hp);
  uint4 q1B = *(const uint4*)(q1p + 16), q2B = *(const uint4*)(q2p + 16),
        hB  = *(const uint4*)(hp + 16);

#pragma unroll 2
  for (int t2 = 0; t2 < 32; ++t2) {
    const int ch0 = 2 * t2, ch1 = 2 * t2 + 1;
    const int pf0 = ((ch0 + 2) & 63) * 16, pf1 = ((ch1 + 2) & 63) * 16;

    // ---- even chunk: compute with A-set, prefetch ch0+2 into fresh regs
    const uint4 q1n0 = *(const uint4*)(q1p + pf0);
    const uint4 q2n0 = *(const uint4*)(q2p + pf0);
    const uint4 hn0  = *(const uint4*)(hp + pf0);
    {
      const uint4 Av = sA[ch0 * 64 + lane];
      const h2 e0 = __builtin_elementwise_max(P1 * as_h2(q1A.x), P2 * as_h2(q2A.x)) * as_h2(Av.x);
      const h2 e1 = __builtin_elementwise_max(P1 * as_h2(q1A.y), P2 * as_h2(q2A.y)) * as_h2(Av.y);
      const h2 e2 = __builtin_elementwise_max(P1 * as_h2(q1A.z), P2 * as_h2(q2A.z)) * as_h2(Av.z);
      const h2 e3 = __builtin_elementwise_max(P1 * as_h2(q1A.w), P2 * as_h2(q2A.w)) * as_h2(Av.w);
      const v8h af = __builtin_bit_cast(v8h,
          (uint4){as_u32(e0), as_u32(e1), as_u32(e2), as_u32(e3)});
      acc = __builtin_amdgcn_mfma_f32_16x16x32_f16(
          af, __builtin_bit_cast(v8h, hA), acc, 0, 0, 0);
    }
    q1A = q1n0; q2A = q2n0; hA = hn0;

    // ---- odd chunk: compute with B-set, prefetch ch1+2
    const uint4 q1n1 = *(const uint4*)(q1p + pf1);
    const uint4 q2n1 = *(const uint4*)(q2p + pf1);
    const uint4 hn1  = *(const uint4*)(hp + pf1);
    {
      const uint4 Av = sA[ch1 * 64 + lane];
      const h2 e0 = __builtin_elementwise_max(P1 * as_h2(q1B.x), P2 * as_h2(q2B.x)) * as_h2(Av.x);
      const h2 e1 = __builtin_elementwise_max(P1 * as_h2(q1B.y), P2 * as_h2(q2B.y)) * as_h2(Av.y);
      const h2 e2 = __builtin_elementwise_max(P1 * as_h2(q1B.z), P2 * as_h2(q2B.z)) * as_h2(Av.z);
      const h2 e3 = __builtin_elementwise_max(P1 * as_h2(q1B.w), P2 * as_h2(q2B.w)) * as_h2(Av.w);
      const v8h af = __builtin_bit_cast(v8h,
          (uint4){as_u32(e0), as_u32(e1), as_u32(e2), as_u32(e3)});
      acc = __builtin_amdgcn_mfma_f32_16x16x32_f16(
          af, __builtin_bit_cast(v8h, hB), acc, 0, 0, 0);
    }
    q1B = q1n1; q2B = q2n1; hB = hn1;
  }

  // D: col = lane&15, row = q*4 + reg (m89-verified). lsum lives in col 8.
#pragma unroll
  for (int r = 0; r < 4; ++r) {
    const float lsum = __shfl(acc[r], q * 16 + 8);
    if (m < 8) {
      out[((long)(b * N_ + i0 + q * 4 + r)) * 128 + hw * 8 + m] = acc[r] / lsum;
    }
  }
}

extern "C" void kernel_launch(void* const* d_in, const int* in_sizes, int n_in,
                              void* d_out, int out_size, void* d_ws, size_t ws_size,
                              hipStream_t stream) {
  const float* nf   = (const float*)d_in[0];
  const float* adj  = (const float*)d_in[1];
  const float* W    = (const float*)d_in[2];
  const float* bias = (const float*)d_in[3];
  const float* a    = (const float*)d_in[4];

  float* out     = (float*)d_out;
  float* adj_out = out + (long)B_ * N_ * H_ * 8;    // 524288 offset

  unsigned* ws  = (unsigned*)d_ws;
  unsigned* hQ  = ws;                    // 32 bh * 16 feats * 1024 dw = 524288
  unsigned* lq1 = ws + 524288;           // 32 bh * 1024 dw = 32768
  unsigned* lq2 = ws + 557056;           // 32768
  float*    lpT = (float*)(ws + 589824); // 65536 floats

  hipLaunchKernelGGL(proj_kernel, dim3(B_ * N_ / 2), dim3(128), 0, stream,
                     nf, W, bias, a, hQ, lq1, lq2, lpT);
  hipLaunchKernelGGL(adjcopy_kernel, dim3(B_ * N_ * N_ / 4096), dim3(256), 0,
                     stream, (const float4*)adj, (float4*)adj_out);
  hipLaunchKernelGGL(attn_kernel, dim3(B_ * (N_ / 16) * 2), dim3(512), 0, stream,
                     adj, hQ, lq1, lq2, lpT, out);
}

// Round 10
// 153.930 us; speedup vs baseline: 1.0395x; 1.0395x over previous
//
#include <hip/hip_runtime.h>
#include <hip/hip_bf16.h>

// GAT layer: B=2, N=2048, C_IN=128, H=16, c=8.
// E(i,j) = exp(lrelu(lp_i+lc_j))*2^-12 = max(P1_i*Q1_j, P2_i*Q2_j)*adj  (f16,
// scale cancels in softmax). Aggregation: mfma_f32_16x16x32_f16, B-operand =
// [h feats (mem) | ones | zeros (lane consts)] -> out + lsum in one acc.
// Round 10: adj copy re-fused into attn staging (r9's separate kernel was a
// net loss); LDS halved to 32KB via two j-halves with restage -> 4 blocks/CU
// target (8 waves/SIMD); proj 8-row blocks with one coalesced uint4 hQ store.
// d_out = [out: B*N*128][adj copy: B*N*N]

#define B_   2
#define N_   2048
#define CIN_ 128
#define H_   16

typedef _Float16 h2  __attribute__((ext_vector_type(2)));
typedef _Float16 v8h __attribute__((ext_vector_type(8)));
typedef float    v4f __attribute__((ext_vector_type(4)));

#define SC6 0.015625f   // 2^-6

__device__ inline h2 pk_f16(float a, float b) {
  return __builtin_bit_cast(h2, __builtin_amdgcn_cvt_pkrtz(a, b));
}
__device__ inline unsigned as_u32(h2 v) { return __builtin_bit_cast(unsigned, v); }
__device__ inline h2 as_h2(unsigned u) { return __builtin_bit_cast(h2, u); }

__global__ __launch_bounds__(128) void proj_kernel(
    const float* __restrict__ nf, const float* __restrict__ W,
    const float* __restrict__ bias, const float* __restrict__ a,
    unsigned* __restrict__ hQ, unsigned* __restrict__ lq1,
    unsigned* __restrict__ lq2, float* __restrict__ lpT) {
  const int row0 = blockIdx.x * 8;       // 8 consecutive rows (same batch)
  const int t    = threadIdx.x;          // output column 0..127
  __shared__ float sNf[8][CIN_];
  {
    const float4* src = (const float4*)(nf + (long)row0 * CIN_);
    float4* dst = (float4*)(&sNf[0][0]);
    dst[t]       = src[t];
    dst[t + 128] = src[t + 128];
  }
  __syncthreads();
  float acc[8];
  const float bv = bias[t];
#pragma unroll
  for (int r = 0; r < 8; ++r) acc[r] = bv;
#pragma unroll 8
  for (int k = 0; k < CIN_; ++k) {
    const float w = W[k * 128 + t];
#pragma unroll
    for (int r = 0; r < 8; ++r) acc[r] = fmaf(sNf[r][k], w, acc[r]);
  }
  const int h = t >> 3, kc = t & 7;
  const int b = row0 >> 11, n0 = row0 & (N_ - 1);
  const int bh = b * H_ + h;
  const int cdw = n0 >> 1;               // j-pair dword index (4-aligned)
  // hQ: feat-major f16 [bh][feat 0..7][j-pair]; one coalesced uint4/thread
  uint4 hv;
  hv.x = as_u32(pk_f16(acc[0], acc[1]));
  hv.y = as_u32(pk_f16(acc[2], acc[3]));
  hv.z = as_u32(pk_f16(acc[4], acc[5]));
  hv.w = as_u32(pk_f16(acc[6], acc[7]));
  *(uint4*)(hQ + ((long)(bh * 8 + kc)) * (N_ / 2) + cdw) = hv;

  const float ap = a[h * 16 + kc], ac = a[h * 16 + 8 + kc];
  float lpv[8], lcv[8];
#pragma unroll
  for (int r = 0; r < 8; ++r) {
    float x = acc[r] * ap, y = acc[r] * ac;
#pragma unroll
    for (int s = 1; s < 8; s <<= 1) {
      x += __shfl_xor(x, s);
      y += __shfl_xor(y, s);
    }
    lpv[r] = x; lcv[r] = y;
  }
  if (kc == 0) {
    float4 l0 = {lpv[0], lpv[1], lpv[2], lpv[3]};
    float4 l1 = {lpv[4], lpv[5], lpv[6], lpv[7]};
    *(float4*)(lpT + (long)bh * N_ + n0)     = l0;
    *(float4*)(lpT + (long)bh * N_ + n0 + 4) = l1;
    uint4 q1, q2;
    q1.x = as_u32(pk_f16(__expf(lcv[0]) * SC6, __expf(lcv[1]) * SC6));
    q1.y = as_u32(pk_f16(__expf(lcv[2]) * SC6, __expf(lcv[3]) * SC6));
    q1.z = as_u32(pk_f16(__expf(lcv[4]) * SC6, __expf(lcv[5]) * SC6));
    q1.w = as_u32(pk_f16(__expf(lcv[6]) * SC6, __expf(lcv[7]) * SC6));
    q2.x = as_u32(pk_f16(__expf(0.2f * lcv[0]) * SC6, __expf(0.2f * lcv[1]) * SC6));
    q2.y = as_u32(pk_f16(__expf(0.2f * lcv[2]) * SC6, __expf(0.2f * lcv[3]) * SC6));
    q2.z = as_u32(pk_f16(__expf(0.2f * lcv[4]) * SC6, __expf(0.2f * lcv[5]) * SC6));
    q2.w = as_u32(pk_f16(__expf(0.2f * lcv[6]) * SC6, __expf(0.2f * lcv[7]) * SC6));
    *(uint4*)(lq1 + (long)bh * (N_ / 2) + cdw) = q1;
    *(uint4*)(lq2 + (long)bh * (N_ / 2) + cdw) = q2;
  }
}

__global__ __launch_bounds__(512) void attn_kernel(
    const float* __restrict__ adj, const unsigned* __restrict__ hQ,
    const unsigned* __restrict__ lq1, const unsigned* __restrict__ lq2,
    const float* __restrict__ lpT, float* __restrict__ out,
    float* __restrict__ adj_out) {
  const int hgroup = blockIdx.x & 1;
  const int rest   = blockIdx.x >> 1;
  const int b      = rest >> 7;          // 128 i-tiles per batch
  const int i0     = (rest & 127) * 16;
  const int tid    = threadIdx.x;
  const int w      = tid >> 6;           // 0..7 (wave = head)
  const int lane   = tid & 63;

  // f16 adjacency half-tile (16 i x 1024 j), 16-B units D = ch*64+q*16+m
  __shared__ uint4 sA[2048];             // 32 KB

  const int hw = hgroup * 8 + w;
  const int bh = b * H_ + hw;
  const int m  = lane & 15;              // A row / B col / D col
  const int q  = lane >> 4;              // k-quad

  const float lp = lpT[(long)bh * N_ + i0 + m];
  const float p1 = __expf(lp) * SC6, p2 = __expf(0.2f * lp) * SC6;
  const h2 P1 = pk_f16(p1, p1), P2 = pk_f16(p2, p2);

  const unsigned* q1b = lq1 + (long)bh * (N_ / 2) + q * 4;
  const unsigned* q2b = lq2 + (long)bh * (N_ / 2) + q * 4;
  const unsigned* hb  = hQ + ((long)(bh * 8 + (m & 7))) * (N_ / 2) + q * 4;
  const bool useH = (m < 8);
  const unsigned cb = (m == 8) ? 0x3C003C00u : 0u;   // ones / zeros column

  v4f acc = {0.0f, 0.0f, 0.0f, 0.0f};

  for (int hj = 0; hj < 2; ++hj) {
    if (hj) __syncthreads();             // waves done reading previous half

    // Stage half-tile (f32 -> f16) + fused adj copy (hgroup 0 only).
    {
      const long aoff = (long)(b * N_ + i0) * N_ + hj * 1024;
      const float* abase = adj + aoff;
      float* obase = adj_out + aoff;
#pragma unroll
      for (int s = 0; s < 4; ++s) {
        const int D = s * 512 + tid;
        const int mm = D & 15, qc = D >> 4;        // qc = ch*4+q
        const int cc = (qc >> 2) * 32 + (qc & 3) * 8;
        const float4 fa = *(const float4*)(abase + mm * N_ + cc);
        const float4 fb = *(const float4*)(abase + mm * N_ + cc + 4);
        uint4 u;
        u.x = as_u32(pk_f16(fa.x, fa.y)); u.y = as_u32(pk_f16(fa.z, fa.w));
        u.z = as_u32(pk_f16(fb.x, fb.y)); u.w = as_u32(pk_f16(fb.z, fb.w));
        sA[D] = u;
        if (hgroup == 0) {
          *(float4*)(obase + mm * N_ + cc)     = fa;
          *(float4*)(obase + mm * N_ + cc + 4) = fb;
        }
      }
    }
    __syncthreads();

    const unsigned* q1p = q1b + hj * 512;
    const unsigned* q2p = q2b + hj * 512;
    const unsigned* hp  = hb + hj * 512;

    // 2-deep pipelined loads over 32 chunks (16 dwords per chunk stride).
    uint4 q1A = *(const uint4*)(q1p),      q2A = *(const uint4*)(q2p),
          hA  = *(const uint4*)(hp);
    uint4 q1B = *(const uint4*)(q1p + 16), q2B = *(const uint4*)(q2p + 16),
          hB  = *(const uint4*)(hp + 16);

    for (int t2 = 0; t2 < 16; ++t2) {
      const int ch0 = 2 * t2, ch1 = 2 * t2 + 1;
      const int pf0 = ((ch0 + 2) & 31) * 16, pf1 = ((ch1 + 2) & 31) * 16;

      const uint4 q1n0 = *(const uint4*)(q1p + pf0);
      const uint4 q2n0 = *(const uint4*)(q2p + pf0);
      const uint4 hn0  = *(const uint4*)(hp + pf0);
      {
        const uint4 Av = sA[ch0 * 64 + lane];
        const h2 e0 = __builtin_elementwise_max(P1 * as_h2(q1A.x), P2 * as_h2(q2A.x)) * as_h2(Av.x);
        const h2 e1 = __builtin_elementwise_max(P1 * as_h2(q1A.y), P2 * as_h2(q2A.y)) * as_h2(Av.y);
        const h2 e2 = __builtin_elementwise_max(P1 * as_h2(q1A.z), P2 * as_h2(q2A.z)) * as_h2(Av.z);
        const h2 e3 = __builtin_elementwise_max(P1 * as_h2(q1A.w), P2 * as_h2(q2A.w)) * as_h2(Av.w);
        uint4 Hs;
        Hs.x = useH ? hA.x : cb; Hs.y = useH ? hA.y : cb;
        Hs.z = useH ? hA.z : cb; Hs.w = useH ? hA.w : cb;
        const v8h af = __builtin_bit_cast(v8h,
            (uint4){as_u32(e0), as_u32(e1), as_u32(e2), as_u32(e3)});
        acc = __builtin_amdgcn_mfma_f32_16x16x32_f16(
            af, __builtin_bit_cast(v8h, Hs), acc, 0, 0, 0);
      }
      q1A = q1n0; q2A = q2n0; hA = hn0;

      const uint4 q1n1 = *(const uint4*)(q1p + pf1);
      const uint4 q2n1 = *(const uint4*)(q2p + pf1);
      const uint4 hn1  = *(const uint4*)(hp + pf1);
      {
        const uint4 Av = sA[ch1 * 64 + lane];
        const h2 e0 = __builtin_elementwise_max(P1 * as_h2(q1B.x), P2 * as_h2(q2B.x)) * as_h2(Av.x);
        const h2 e1 = __builtin_elementwise_max(P1 * as_h2(q1B.y), P2 * as_h2(q2B.y)) * as_h2(Av.y);
        const h2 e2 = __builtin_elementwise_max(P1 * as_h2(q1B.z), P2 * as_h2(q2B.z)) * as_h2(Av.z);
        const h2 e3 = __builtin_elementwise_max(P1 * as_h2(q1B.w), P2 * as_h2(q2B.w)) * as_h2(Av.w);
        uint4 Hs;
        Hs.x = useH ? hB.x : cb; Hs.y = useH ? hB.y : cb;
        Hs.z = useH ? hB.z : cb; Hs.w = useH ? hB.w : cb;
        const v8h af = __builtin_bit_cast(v8h,
            (uint4){as_u32(e0), as_u32(e1), as_u32(e2), as_u32(e3)});
        acc = __builtin_amdgcn_mfma_f32_16x16x32_f16(
            af, __builtin_bit_cast(v8h, Hs), acc, 0, 0, 0);
      }
      q1B = q1n1; q2B = q2n1; hB = hn1;
    }
  }

  // D: col = lane&15, row = q*4 + reg (m89-verified). lsum lives in col 8.
#pragma unroll
  for (int r = 0; r < 4; ++r) {
    const float lsum = __shfl(acc[r], q * 16 + 8);
    if (m < 8) {
      out[((long)(b * N_ + i0 + q * 4 + r)) * 128 + hw * 8 + m] = acc[r] / lsum;
    }
  }
}

extern "C" void kernel_launch(void* const* d_in, const int* in_sizes, int n_in,
                              void* d_out, int out_size, void* d_ws, size_t ws_size,
                              hipStream_t stream) {
  const float* nf   = (const float*)d_in[0];
  const float* adj  = (const float*)d_in[1];
  const float* W    = (const float*)d_in[2];
  const float* bias = (const float*)d_in[3];
  const float* a    = (const float*)d_in[4];

  float* out     = (float*)d_out;
  float* adj_out = out + (long)B_ * N_ * H_ * 8;    // 524288 offset

  unsigned* ws  = (unsigned*)d_ws;
  unsigned* hQ  = ws;                    // 32 bh * 8 feats * 1024 dw = 262144
  unsigned* lq1 = ws + 262144;           // 32 bh * 1024 dw = 32768
  unsigned* lq2 = ws + 294912;           // 32768
  float*    lpT = (float*)(ws + 327680); // 65536 floats

  hipLaunchKernelGGL(proj_kernel, dim3(B_ * N_ / 8), dim3(128), 0, stream,
                     nf, W, bias, a, hQ, lq1, lq2, lpT);
  hipLaunchKernelGGL(attn_kernel, dim3(B_ * (N_ / 16) * 2), dim3(512), 0, stream,
                     adj, hQ, lq1, lq2, lpT, out, adj_out);
}

// Round 11
// 144.586 us; speedup vs baseline: 1.1067x; 1.0646x over previous
//
#include <hip/hip_runtime.h>
#include <hip/hip_bf16.h>

// GAT layer: B=2, N=2048, C_IN=128, H=16, c=8.
// E(i,j) = exp(lrelu(lp_i+lc_j))*2^-12 = max(P1_i*Q1_j, P2_i*Q2_j)*adj  (f16,
// scale cancels in softmax). Aggregation: mfma_f32_16x16x32_f16, B-operand =
// [h feats | ones-buffer for lanes m>=8] -> out cols 0..7 + lsum in col 8.
// Round 11: j split across blocks (grid 512->1024, latency hiding was grid-
// capped at 2 blocks/CU); partial acc+lsum to ws + combine kernel; q1/q2
// interleaved (one cache line per chunk); ones-buffer replaces per-chunk
// cndmasks. d_out = [out: B*N*128][adj copy: B*N*N]

#define B_   2
#define N_   2048
#define CIN_ 128
#define H_   16

typedef _Float16 h2  __attribute__((ext_vector_type(2)));
typedef _Float16 v8h __attribute__((ext_vector_type(8)));
typedef float    v4f __attribute__((ext_vector_type(4)));

#define SC6 0.015625f   // 2^-6

__device__ inline h2 pk_f16(float a, float b) {
  return __builtin_bit_cast(h2, __builtin_amdgcn_cvt_pkrtz(a, b));
}
__device__ inline unsigned as_u32(h2 v) { return __builtin_bit_cast(unsigned, v); }
__device__ inline h2 as_h2(unsigned u) { return __builtin_bit_cast(h2, u); }

__global__ __launch_bounds__(128) void proj_kernel(
    const float* __restrict__ nf, const float* __restrict__ W,
    const float* __restrict__ bias, const float* __restrict__ a,
    unsigned* __restrict__ hQ, unsigned* __restrict__ qI,
    float* __restrict__ lpT, unsigned* __restrict__ ones) {
  const int row0 = blockIdx.x * 8;       // 8 consecutive rows (same batch)
  const int t    = threadIdx.x;          // output column 0..127
  if (blockIdx.x == 0) {                 // ones-buffer for B-operand cols 8..15
    ones[t] = 0x3C003C00u; ones[t + 128] = 0x3C003C00u;
    ones[t + 256] = 0x3C003C00u; ones[t + 384] = 0x3C003C00u;
  }
  __shared__ float sNf[8][CIN_];
  {
    const float4* src = (const float4*)(nf + (long)row0 * CIN_);
    float4* dst = (float4*)(&sNf[0][0]);
    dst[t]       = src[t];
    dst[t + 128] = src[t + 128];
  }
  __syncthreads();
  float acc[8];
  const float bv = bias[t];
#pragma unroll
  for (int r = 0; r < 8; ++r) acc[r] = bv;
#pragma unroll 8
  for (int k = 0; k < CIN_; ++k) {
    const float w = W[k * 128 + t];
#pragma unroll
    for (int r = 0; r < 8; ++r) acc[r] = fmaf(sNf[r][k], w, acc[r]);
  }
  const int h = t >> 3, kc = t & 7;
  const int b = row0 >> 11, n0 = row0 & (N_ - 1);
  const int bh = b * H_ + h;
  const int cdw = n0 >> 1;               // j-pair dword index (4-aligned)
  // hQ: feat-major f16 [bh][feat 0..7][j-pair]; one coalesced uint4/thread
  uint4 hv;
  hv.x = as_u32(pk_f16(acc[0], acc[1]));
  hv.y = as_u32(pk_f16(acc[2], acc[3]));
  hv.z = as_u32(pk_f16(acc[4], acc[5]));
  hv.w = as_u32(pk_f16(acc[6], acc[7]));
  *(uint4*)(hQ + ((long)(bh * 8 + kc)) * (N_ / 2) + cdw) = hv;

  const float ap = a[h * 16 + kc], ac = a[h * 16 + 8 + kc];
  float lpv[8], lcv[8];
#pragma unroll
  for (int r = 0; r < 8; ++r) {
    float x = acc[r] * ap, y = acc[r] * ac;
#pragma unroll
    for (int s = 1; s < 8; s <<= 1) {
      x += __shfl_xor(x, s);
      y += __shfl_xor(y, s);
    }
    lpv[r] = x; lcv[r] = y;
  }
  if (kc == 0) {
    float4 l0 = {lpv[0], lpv[1], lpv[2], lpv[3]};
    float4 l1 = {lpv[4], lpv[5], lpv[6], lpv[7]};
    *(float4*)(lpT + (long)bh * N_ + n0)     = l0;
    *(float4*)(lpT + (long)bh * N_ + n0 + 4) = l1;
    uint4 q1, q2;
    q1.x = as_u32(pk_f16(__expf(lcv[0]) * SC6, __expf(lcv[1]) * SC6));
    q1.y = as_u32(pk_f16(__expf(lcv[2]) * SC6, __expf(lcv[3]) * SC6));
    q1.z = as_u32(pk_f16(__expf(lcv[4]) * SC6, __expf(lcv[5]) * SC6));
    q1.w = as_u32(pk_f16(__expf(lcv[6]) * SC6, __expf(lcv[7]) * SC6));
    q2.x = as_u32(pk_f16(__expf(0.2f * lcv[0]) * SC6, __expf(0.2f * lcv[1]) * SC6));
    q2.y = as_u32(pk_f16(__expf(0.2f * lcv[2]) * SC6, __expf(0.2f * lcv[3]) * SC6));
    q2.z = as_u32(pk_f16(__expf(0.2f * lcv[4]) * SC6, __expf(0.2f * lcv[5]) * SC6));
    q2.w = as_u32(pk_f16(__expf(0.2f * lcv[6]) * SC6, __expf(0.2f * lcv[7]) * SC6));
    // interleaved: per chunk (16 pairs) 32 dw = [quad0: q1x4 q2x4]..[quad3]
    const int addr = bh * 2048 + (cdw >> 4) * 32 + ((cdw >> 2) & 3) * 8;
    *(uint4*)(qI + addr)     = q1;
    *(uint4*)(qI + addr + 4) = q2;
  }
}

__global__ __launch_bounds__(512) void attn_kernel(
    const float* __restrict__ adj, const unsigned* __restrict__ hQ,
    const unsigned* __restrict__ qI, const float* __restrict__ lpT,
    const unsigned* __restrict__ ones, float* __restrict__ pA,
    float* __restrict__ pL, float* __restrict__ adj_out) {
  const int jh     = blockIdx.x & 1;     // j-half
  const int hgroup = (blockIdx.x >> 1) & 1;
  const int rest   = blockIdx.x >> 2;
  const int b      = rest >> 7;          // 128 i-tiles per batch
  const int i0     = (rest & 127) * 16;
  const int tid    = threadIdx.x;
  const int w      = tid >> 6;           // 0..7 (wave = head)
  const int lane   = tid & 63;

  // f16 adjacency strip (16 i x 1024 j), 16-B units D = ch*64+q*16+m
  __shared__ uint4 sA[2048];             // 32 KB

  // Stage strip (f32 -> f16) + fused adj copy (hgroup 0 copies its strip).
  {
    const long aoff = (long)(b * N_ + i0) * N_ + jh * 1024;
    const float* abase = adj + aoff;
    float* obase = adj_out + aoff;
#pragma unroll
    for (int s = 0; s < 4; ++s) {
      const int D = s * 512 + tid;
      const int mm = D & 15, qc = D >> 4;          // qc = ch*4+q
      const int cc = (qc >> 2) * 32 + (qc & 3) * 8;
      const float4 fa = *(const float4*)(abase + mm * N_ + cc);
      const float4 fb = *(const float4*)(abase + mm * N_ + cc + 4);
      uint4 u;
      u.x = as_u32(pk_f16(fa.x, fa.y)); u.y = as_u32(pk_f16(fa.z, fa.w));
      u.z = as_u32(pk_f16(fb.x, fb.y)); u.w = as_u32(pk_f16(fb.z, fb.w));
      sA[D] = u;
      if (hgroup == 0) {
        *(float4*)(obase + mm * N_ + cc)     = fa;
        *(float4*)(obase + mm * N_ + cc + 4) = fb;
      }
    }
  }
  __syncthreads();

  const int hw = hgroup * 8 + w;
  const int bh = b * H_ + hw;
  const int m  = lane & 15;              // A row / B col / D col
  const int q  = lane >> 4;              // k-quad

  const float lp = lpT[(long)bh * N_ + i0 + m];
  const float p1 = __expf(lp) * SC6, p2 = __expf(0.2f * lp) * SC6;
  const h2 P1 = pk_f16(p1, p1), P2 = pk_f16(p2, p2);

  const unsigned* qp = qI + bh * 2048 + jh * 1024 + q * 8;
  const unsigned* hp = (m < 8) ? hQ + ((long)(bh * 8 + m)) * (N_ / 2) + jh * 512 + q * 4
                               : ones + q * 4;

  v4f acc = {0.0f, 0.0f, 0.0f, 0.0f};

  // 2-deep pipelined loads over 32 chunks (qI stride 32 dw, hQ stride 16 dw).
  uint4 q1A = *(const uint4*)(qp),      q2A = *(const uint4*)(qp + 4),
        hA  = *(const uint4*)(hp);
  uint4 q1B = *(const uint4*)(qp + 32), q2B = *(const uint4*)(qp + 36),
        hB  = *(const uint4*)(hp + 16);

  for (int t2 = 0; t2 < 16; ++t2) {
    const int ch0 = 2 * t2, ch1 = 2 * t2 + 1;
    const int pq0 = ((ch0 + 2) & 31) * 32, ph0 = ((ch0 + 2) & 31) * 16;
    const int pq1 = ((ch1 + 2) & 31) * 32, ph1 = ((ch1 + 2) & 31) * 16;

    const uint4 q1n0 = *(const uint4*)(qp + pq0);
    const uint4 q2n0 = *(const uint4*)(qp + pq0 + 4);
    const uint4 hn0  = *(const uint4*)(hp + ph0);
    {
      const uint4 Av = sA[ch0 * 64 + lane];
      const h2 e0 = __builtin_elementwise_max(P1 * as_h2(q1A.x), P2 * as_h2(q2A.x)) * as_h2(Av.x);
      const h2 e1 = __builtin_elementwise_max(P1 * as_h2(q1A.y), P2 * as_h2(q2A.y)) * as_h2(Av.y);
      const h2 e2 = __builtin_elementwise_max(P1 * as_h2(q1A.z), P2 * as_h2(q2A.z)) * as_h2(Av.z);
      const h2 e3 = __builtin_elementwise_max(P1 * as_h2(q1A.w), P2 * as_h2(q2A.w)) * as_h2(Av.w);
      const v8h af = __builtin_bit_cast(v8h,
          (uint4){as_u32(e0), as_u32(e1), as_u32(e2), as_u32(e3)});
      acc = __builtin_amdgcn_mfma_f32_16x16x32_f16(
          af, __builtin_bit_cast(v8h, hA), acc, 0, 0, 0);
    }
    q1A = q1n0; q2A = q2n0; hA = hn0;

    const uint4 q1n1 = *(const uint4*)(qp + pq1);
    const uint4 q2n1 = *(const uint4*)(qp + pq1 + 4);
    const uint4 hn1  = *(const uint4*)(hp + ph1);
    {
      const uint4 Av = sA[ch1 * 64 + lane];
      const h2 e0 = __builtin_elementwise_max(P1 * as_h2(q1B.x), P2 * as_h2(q2B.x)) * as_h2(Av.x);
      const h2 e1 = __builtin_elementwise_max(P1 * as_h2(q1B.y), P2 * as_h2(q2B.y)) * as_h2(Av.y);
      const h2 e2 = __builtin_elementwise_max(P1 * as_h2(q1B.z), P2 * as_h2(q2B.z)) * as_h2(Av.z);
      const h2 e3 = __builtin_elementwise_max(P1 * as_h2(q1B.w), P2 * as_h2(q2B.w)) * as_h2(Av.w);
      const v8h af = __builtin_bit_cast(v8h,
          (uint4){as_u32(e0), as_u32(e1), as_u32(e2), as_u32(e3)});
      acc = __builtin_amdgcn_mfma_f32_16x16x32_f16(
          af, __builtin_bit_cast(v8h, hB), acc, 0, 0, 0);
    }
    q1B = q1n1; q2B = q2n1; hB = hn1;
  }

  // D: col = lane&15, row = q*4 + reg. Write partials (no division).
#pragma unroll
  for (int r = 0; r < 4; ++r) {
    const int gidx = (b * N_ + i0 + q * 4 + r) * H_ + hw;
    if (m < 8)   pA[(long)jh * 524288 + (long)gidx * 8 + m] = acc[r];
    if (m == 8)  pL[jh * 65536 + gidx] = acc[r];
  }
}

__global__ __launch_bounds__(512) void combine_kernel(
    const float* __restrict__ pA, const float* __restrict__ pL,
    float* __restrict__ out) {
  const int g = blockIdx.x * 512 + threadIdx.x;    // = ((b*N+i)*16+h)*8+k
  const float s = pL[g >> 3] + pL[(g >> 3) + 65536];
  const float v = pA[g] + pA[g + 524288];
  out[g] = v / s;
}

extern "C" void kernel_launch(void* const* d_in, const int* in_sizes, int n_in,
                              void* d_out, int out_size, void* d_ws, size_t ws_size,
                              hipStream_t stream) {
  const float* nf   = (const float*)d_in[0];
  const float* adj  = (const float*)d_in[1];
  const float* W    = (const float*)d_in[2];
  const float* bias = (const float*)d_in[3];
  const float* a    = (const float*)d_in[4];

  float* out     = (float*)d_out;
  float* adj_out = out + (long)B_ * N_ * H_ * 8;    // 524288 offset

  unsigned* ws   = (unsigned*)d_ws;
  unsigned* hQ   = ws;                       // 32 bh * 8 feats * 1024 dw = 262144
  unsigned* qI   = ws + 262144;              // 32 bh * 2048 dw = 65536
  float*    lpT  = (float*)(ws + 327680);    // 65536 floats
  unsigned* ones = ws + 393216;              // 512 dw
  float*    pA   = (float*)(ws + 393728);    // 2 * 524288 floats
  float*    pL   = (float*)(ws + 1442304);   // 2 * 65536 floats

  hipLaunchKernelGGL(proj_kernel, dim3(B_ * N_ / 8), dim3(128), 0, stream,
                     nf, W, bias, a, hQ, qI, lpT, ones);
  hipLaunchKernelGGL(attn_kernel, dim3(B_ * (N_ / 16) * 2 * 2), dim3(512), 0,
                     stream, adj, hQ, qI, lpT, ones, pA, pL, adj_out);
  hipLaunchKernelGGL(combine_kernel, dim3(1024), dim3(512), 0, stream,
                     pA, pL, out);
}

// Round 12
// 131.425 us; speedup vs baseline: 1.2175x; 1.1001x over previous
//
#include <hip/hip_runtime.h>
#include <hip/hip_bf16.h>

// GAT layer: B=2, N=2048, C_IN=128, H=16, c=8.
// E(i,j) = exp(lrelu(lp_i+lc_j))*2^-12 = max(P1_i*Q1_j, P2_i*Q2_j)*adj  (f16).
// Aggregation: mfma_f32_16x16x32_f16; B-operand = [h feats | ones buffer].
// Round 12: 2 i-tiles (32 rows) per wave -> 2 MFMAs share each q1/q2/h load
// (r11 was dependent-load latency-bound at 3 loads/MFMA); j in 4 quarters,
// 4-way partial combine; proj re-gridded to 4-row blocks (2x waves).
// d_out = [out: B*N*128][adj copy: B*N*N]

#define B_   2
#define N_   2048
#define CIN_ 128
#define H_   16

typedef _Float16 h2  __attribute__((ext_vector_type(2)));
typedef _Float16 v8h __attribute__((ext_vector_type(8)));
typedef float    v4f __attribute__((ext_vector_type(4)));

#define SC6 0.015625f   // 2^-6

__device__ inline h2 pk_f16(float a, float b) {
  return __builtin_bit_cast(h2, __builtin_amdgcn_cvt_pkrtz(a, b));
}
__device__ inline unsigned as_u32(h2 v) { return __builtin_bit_cast(unsigned, v); }
__device__ inline h2 as_h2(unsigned u) { return __builtin_bit_cast(h2, u); }

__global__ __launch_bounds__(128) void proj_kernel(
    const float* __restrict__ nf, const float* __restrict__ W,
    const float* __restrict__ bias, const float* __restrict__ a,
    unsigned* __restrict__ hQ, unsigned* __restrict__ qI,
    float* __restrict__ lpT, unsigned* __restrict__ ones) {
  const int row0 = blockIdx.x * 4;       // 4 consecutive rows (same batch)
  const int t    = threadIdx.x;          // output column 0..127
  if (blockIdx.x == 0) {                 // ones-buffer for B-operand cols 8..15
    ones[t] = 0x3C003C00u; ones[t + 128] = 0x3C003C00u;
    ones[t + 256] = 0x3C003C00u; ones[t + 384] = 0x3C003C00u;
  }
  __shared__ float sNf[4][CIN_];
  ((float4*)&sNf[0][0])[t] = ((const float4*)(nf + (long)row0 * CIN_))[t];
  __syncthreads();
  float acc[4];
  const float bv = bias[t];
#pragma unroll
  for (int r = 0; r < 4; ++r) acc[r] = bv;
#pragma unroll 8
  for (int k = 0; k < CIN_; ++k) {
    const float w = W[k * 128 + t];
#pragma unroll
    for (int r = 0; r < 4; ++r) acc[r] = fmaf(sNf[r][k], w, acc[r]);
  }
  const int h = t >> 3, kc = t & 7;
  const int b = row0 >> 11, n0 = row0 & (N_ - 1);
  const int bh = b * H_ + h;
  const int cdw = n0 >> 1;               // j-pair dword index (2-aligned)
  uint2 hv;
  hv.x = as_u32(pk_f16(acc[0], acc[1]));
  hv.y = as_u32(pk_f16(acc[2], acc[3]));
  *(uint2*)(hQ + ((long)(bh * 8 + kc)) * (N_ / 2) + cdw) = hv;

  const float ap = a[h * 16 + kc], ac = a[h * 16 + 8 + kc];
  float lpv[4], lcv[4];
#pragma unroll
  for (int r = 0; r < 4; ++r) {
    float x = acc[r] * ap, y = acc[r] * ac;
#pragma unroll
    for (int s = 1; s < 8; s <<= 1) {
      x += __shfl_xor(x, s);
      y += __shfl_xor(y, s);
    }
    lpv[r] = x; lcv[r] = y;
  }
  if (kc == 0) {
    float4 l0 = {lpv[0], lpv[1], lpv[2], lpv[3]};
    *(float4*)(lpT + (long)bh * N_ + n0) = l0;
    uint2 q1, q2;
    q1.x = as_u32(pk_f16(__expf(lcv[0]) * SC6, __expf(lcv[1]) * SC6));
    q1.y = as_u32(pk_f16(__expf(lcv[2]) * SC6, __expf(lcv[3]) * SC6));
    q2.x = as_u32(pk_f16(__expf(0.2f * lcv[0]) * SC6, __expf(0.2f * lcv[1]) * SC6));
    q2.y = as_u32(pk_f16(__expf(0.2f * lcv[2]) * SC6, __expf(0.2f * lcv[3]) * SC6));
    // interleave: chunk(16 pairs)=32dw: [q1 quad0|q2 quad0|...|q1 quad3|q2 quad3]
    const int addr = bh * 2048 + (cdw >> 4) * 32 + ((cdw >> 2) & 3) * 8;
    const int off  = cdw & 3;            // 0 or 2
    *(uint2*)(qI + addr + off)     = q1;
    *(uint2*)(qI + addr + 4 + off) = q2;
  }
}

__global__ __launch_bounds__(512) void attn_kernel(
    const float* __restrict__ adj, const unsigned* __restrict__ hQ,
    const unsigned* __restrict__ qI, const float* __restrict__ lpT,
    const unsigned* __restrict__ ones, float* __restrict__ pA,
    float* __restrict__ pL, float* __restrict__ adj_out) {
  const int jq     = blockIdx.x & 3;     // j-quarter (512 wide)
  const int hgroup = (blockIdx.x >> 2) & 1;
  const int rest   = blockIdx.x >> 3;
  const int b      = rest >> 6;          // 64 i-tiles (32-row) per batch
  const int i0     = (rest & 63) * 32;
  const int tid    = threadIdx.x;
  const int w      = tid >> 6;           // 0..7 (wave = head)
  const int lane   = tid & 63;

  // Two 16x512 f16 regions; unit D(u,ch,q,m) = u*1024 + ch*64 + q*16 + m
  __shared__ uint4 sA[2048];             // 32 KB

  // Stage strip (f32 -> f16) + fused adj copy (hgroup 0 copies its strip).
  {
    const long aoff = (long)(b * N_ + i0) * N_ + jq * 512;
    const float* abase = adj + aoff;
    float* obase = adj_out + aoff;
#pragma unroll
    for (int s = 0; s < 4; ++s) {
      const int D = s * 512 + tid;
      const int u = D >> 10, loc = D & 1023;
      const int mm = loc & 15, qc = loc >> 4;      // qc = ch*4+q
      const int cc = (qc >> 2) * 32 + (qc & 3) * 8;
      const int row = u * 16 + mm;
      const float4 fa = *(const float4*)(abase + (long)row * N_ + cc);
      const float4 fb = *(const float4*)(abase + (long)row * N_ + cc + 4);
      uint4 uu;
      uu.x = as_u32(pk_f16(fa.x, fa.y)); uu.y = as_u32(pk_f16(fa.z, fa.w));
      uu.z = as_u32(pk_f16(fb.x, fb.y)); uu.w = as_u32(pk_f16(fb.z, fb.w));
      sA[D] = uu;
      if (hgroup == 0) {
        *(float4*)(obase + (long)row * N_ + cc)     = fa;
        *(float4*)(obase + (long)row * N_ + cc + 4) = fb;
      }
    }
  }
  __syncthreads();

  const int hw = hgroup * 8 + w;
  const int bh = b * H_ + hw;
  const int m  = lane & 15;              // A row / B col / D col
  const int q  = lane >> 4;              // k-quad

  const float lpa = lpT[(long)bh * N_ + i0 + m];
  const float lpb = lpT[(long)bh * N_ + i0 + 16 + m];
  const h2 P1a = pk_f16(__expf(lpa) * SC6, __expf(lpa) * SC6);
  const h2 P2a = pk_f16(__expf(0.2f * lpa) * SC6, __expf(0.2f * lpa) * SC6);
  const h2 P1b = pk_f16(__expf(lpb) * SC6, __expf(lpb) * SC6);
  const h2 P2b = pk_f16(__expf(0.2f * lpb) * SC6, __expf(0.2f * lpb) * SC6);

  const unsigned* qp = qI + bh * 2048 + jq * 512 + q * 8;
  const unsigned* hp = (m < 8)
      ? hQ + ((long)(bh * 8 + m)) * (N_ / 2) + jq * 256 + q * 4
      : ones + q * 4;

  v4f acc0 = {0.0f, 0.0f, 0.0f, 0.0f};
  v4f acc1 = {0.0f, 0.0f, 0.0f, 0.0f};

  // 2-deep pipelined loads over 16 chunks (qI stride 32 dw, hQ stride 16 dw).
  uint4 q1A = *(const uint4*)(qp),      q2A = *(const uint4*)(qp + 4),
        hA  = *(const uint4*)(hp);
  uint4 q1B = *(const uint4*)(qp + 32), q2B = *(const uint4*)(qp + 36),
        hB  = *(const uint4*)(hp + 16);

  for (int t2 = 0; t2 < 8; ++t2) {
    const int ch0 = 2 * t2, ch1 = 2 * t2 + 1;
    const int pq0 = ((ch0 + 2) & 15) * 32, ph0 = ((ch0 + 2) & 15) * 16;
    const int pq1 = ((ch1 + 2) & 15) * 32, ph1 = ((ch1 + 2) & 15) * 16;

    const uint4 q1n0 = *(const uint4*)(qp + pq0);
    const uint4 q2n0 = *(const uint4*)(qp + pq0 + 4);
    const uint4 hn0  = *(const uint4*)(hp + ph0);
    {
      const uint4 Av0 = sA[ch0 * 64 + lane];
      const uint4 Av1 = sA[1024 + ch0 * 64 + lane];
      const v8h bf = __builtin_bit_cast(v8h, hA);
      const h2 Q1x = as_h2(q1A.x), Q1y = as_h2(q1A.y), Q1z = as_h2(q1A.z), Q1w = as_h2(q1A.w);
      const h2 Q2x = as_h2(q2A.x), Q2y = as_h2(q2A.y), Q2z = as_h2(q2A.z), Q2w = as_h2(q2A.w);
      const uint4 af0 = {
        as_u32(__builtin_elementwise_max(P1a * Q1x, P2a * Q2x) * as_h2(Av0.x)),
        as_u32(__builtin_elementwise_max(P1a * Q1y, P2a * Q2y) * as_h2(Av0.y)),
        as_u32(__builtin_elementwise_max(P1a * Q1z, P2a * Q2z) * as_h2(Av0.z)),
        as_u32(__builtin_elementwise_max(P1a * Q1w, P2a * Q2w) * as_h2(Av0.w))};
      acc0 = __builtin_amdgcn_mfma_f32_16x16x32_f16(
          __builtin_bit_cast(v8h, af0), bf, acc0, 0, 0, 0);
      const uint4 af1 = {
        as_u32(__builtin_elementwise_max(P1b * Q1x, P2b * Q2x) * as_h2(Av1.x)),
        as_u32(__builtin_elementwise_max(P1b * Q1y, P2b * Q2y) * as_h2(Av1.y)),
        as_u32(__builtin_elementwise_max(P1b * Q1z, P2b * Q2z) * as_h2(Av1.z)),
        as_u32(__builtin_elementwise_max(P1b * Q1w, P2b * Q2w) * as_h2(Av1.w))};
      acc1 = __builtin_amdgcn_mfma_f32_16x16x32_f16(
          __builtin_bit_cast(v8h, af1), bf, acc1, 0, 0, 0);
    }
    q1A = q1n0; q2A = q2n0; hA = hn0;

    const uint4 q1n1 = *(const uint4*)(qp + pq1);
    const uint4 q2n1 = *(const uint4*)(qp + pq1 + 4);
    const uint4 hn1  = *(const uint4*)(hp + ph1);
    {
      const uint4 Av0 = sA[ch1 * 64 + lane];
      const uint4 Av1 = sA[1024 + ch1 * 64 + lane];
      const v8h bf = __builtin_bit_cast(v8h, hB);
      const h2 Q1x = as_h2(q1B.x), Q1y = as_h2(q1B.y), Q1z = as_h2(q1B.z), Q1w = as_h2(q1B.w);
      const h2 Q2x = as_h2(q2B.x), Q2y = as_h2(q2B.y), Q2z = as_h2(q2B.z), Q2w = as_h2(q2B.w);
      const uint4 af0 = {
        as_u32(__builtin_elementwise_max(P1a * Q1x, P2a * Q2x) * as_h2(Av0.x)),
        as_u32(__builtin_elementwise_max(P1a * Q1y, P2a * Q2y) * as_h2(Av0.y)),
        as_u32(__builtin_elementwise_max(P1a * Q1z, P2a * Q2z) * as_h2(Av0.z)),
        as_u32(__builtin_elementwise_max(P1a * Q1w, P2a * Q2w) * as_h2(Av0.w))};
      acc0 = __builtin_amdgcn_mfma_f32_16x16x32_f16(
          __builtin_bit_cast(v8h, af0), bf, acc0, 0, 0, 0);
      const uint4 af1 = {
        as_u32(__builtin_elementwise_max(P1b * Q1x, P2b * Q2x) * as_h2(Av1.x)),
        as_u32(__builtin_elementwise_max(P1b * Q1y, P2b * Q2y) * as_h2(Av1.y)),
        as_u32(__builtin_elementwise_max(P1b * Q1z, P2b * Q2z) * as_h2(Av1.z)),
        as_u32(__builtin_elementwise_max(P1b * Q1w, P2b * Q2w) * as_h2(Av1.w))};
      acc1 = __builtin_amdgcn_mfma_f32_16x16x32_f16(
          __builtin_bit_cast(v8h, af1), bf, acc1, 0, 0, 0);
    }
    q1B = q1n1; q2B = q2n1; hB = hn1;
  }

  // D: col = lane&15, row = q*4 + reg. Write partials (no division).
#pragma unroll
  for (int u = 0; u < 2; ++u) {
    const v4f av = u ? acc1 : acc0;
#pragma unroll
    for (int r = 0; r < 4; ++r) {
      const int gidx = (b * N_ + i0 + u * 16 + q * 4 + r) * H_ + hw;
      if (m < 8)  pA[jq * 524288 + (long)gidx * 8 + m] = av[r];
      if (m == 8) pL[jq * 65536 + gidx] = av[r];
    }
  }
}

__global__ __launch_bounds__(512) void combine_kernel(
    const float* __restrict__ pA, const float* __restrict__ pL,
    float* __restrict__ out) {
  const int g = blockIdx.x * 512 + threadIdx.x;    // = ((b*N+i)*16+h)*8+k
  const int gl = g >> 3;
  const float s = pL[gl] + pL[gl + 65536] + pL[gl + 131072] + pL[gl + 196608];
  const float v = pA[g] + pA[g + 524288] + pA[g + 1048576] + pA[g + 1572864];
  out[g] = v / s;
}

extern "C" void kernel_launch(void* const* d_in, const int* in_sizes, int n_in,
                              void* d_out, int out_size, void* d_ws, size_t ws_size,
                              hipStream_t stream) {
  const float* nf   = (const float*)d_in[0];
  const float* adj  = (const float*)d_in[1];
  const float* W    = (const float*)d_in[2];
  const float* bias = (const float*)d_in[3];
  const float* a    = (const float*)d_in[4];

  float* out     = (float*)d_out;
  float* adj_out = out + (long)B_ * N_ * H_ * 8;    // 524288 offset

  unsigned* ws   = (unsigned*)d_ws;
  unsigned* hQ   = ws;                       // 262144 dw
  unsigned* qI   = ws + 262144;              // 65536 dw
  float*    lpT  = (float*)(ws + 327680);    // 65536 floats
  unsigned* ones = ws + 393216;              // 512 dw
  float*    pA   = (float*)(ws + 393728);    // 4 * 524288 floats
  float*    pL   = (float*)(ws + 2490880);   // 4 * 65536 floats

  hipLaunchKernelGGL(proj_kernel, dim3(B_ * N_ / 4), dim3(128), 0, stream,
                     nf, W, bias, a, hQ, qI, lpT, ones);
  hipLaunchKernelGGL(attn_kernel, dim3(B_ * (N_ / 32) * 2 * 4), dim3(512), 0,
                     stream, adj, hQ, qI, lpT, ones, pA, pL, adj_out);
  hipLaunchKernelGGL(combine_kernel, dim3(1024), dim3(512), 0, stream,
                     pA, pL, out);
}

// Round 13
// 131.100 us; speedup vs baseline: 1.2205x; 1.0025x over previous
//
#include <hip/hip_runtime.h>
#include <hip/hip_bf16.h>

// GAT layer: B=2, N=2048, C_IN=128, H=16, c=8.
// E(i,j) = exp(lrelu(lp_i+lc_j))*2^-12 = max(P1_i*Q1_j, P2_i*Q2_j)*adj  (f16).
// Aggregation: mfma_f32_16x16x32_f16; B-operand = [h feats | ones buffer].
// Round 13: both head-groups merged into one block -> each wave = 2 heads x
// 2 i-tiles = 4 MFMAs/chunk; adjacency staged+copied once per strip (was
// twice); grid 512 (2 blocks/CU), staging loads hoisted for MLP.
// d_out = [out: B*N*128][adj copy: B*N*N]

#define B_   2
#define N_   2048
#define CIN_ 128
#define H_   16

typedef _Float16 h2  __attribute__((ext_vector_type(2)));
typedef _Float16 v8h __attribute__((ext_vector_type(8)));
typedef float    v4f __attribute__((ext_vector_type(4)));

#define SC6 0.015625f   // 2^-6

__device__ inline h2 pk_f16(float a, float b) {
  return __builtin_bit_cast(h2, __builtin_amdgcn_cvt_pkrtz(a, b));
}
__device__ inline unsigned as_u32(h2 v) { return __builtin_bit_cast(unsigned, v); }
__device__ inline h2 as_h2(unsigned u) { return __builtin_bit_cast(h2, u); }

__global__ __launch_bounds__(128) void proj_kernel(
    const float* __restrict__ nf, const float* __restrict__ W,
    const float* __restrict__ bias, const float* __restrict__ a,
    unsigned* __restrict__ hQ, unsigned* __restrict__ qI,
    float* __restrict__ lpT, unsigned* __restrict__ ones) {
  const int row0 = blockIdx.x * 4;       // 4 consecutive rows (same batch)
  const int t    = threadIdx.x;          // output column 0..127
  if (blockIdx.x == 0) {                 // ones-buffer for B-operand cols 8..15
    ones[t] = 0x3C003C00u; ones[t + 128] = 0x3C003C00u;
    ones[t + 256] = 0x3C003C00u; ones[t + 384] = 0x3C003C00u;
  }
  __shared__ float sNf[4][CIN_];
  ((float4*)&sNf[0][0])[t] = ((const float4*)(nf + (long)row0 * CIN_))[t];
  __syncthreads();
  float acc[4];
  const float bv = bias[t];
#pragma unroll
  for (int r = 0; r < 4; ++r) acc[r] = bv;
#pragma unroll 8
  for (int k = 0; k < CIN_; ++k) {
    const float w = W[k * 128 + t];
#pragma unroll
    for (int r = 0; r < 4; ++r) acc[r] = fmaf(sNf[r][k], w, acc[r]);
  }
  const int h = t >> 3, kc = t & 7;
  const int b = row0 >> 11, n0 = row0 & (N_ - 1);
  const int bh = b * H_ + h;
  const int cdw = n0 >> 1;               // j-pair dword index (2-aligned)
  uint2 hv;
  hv.x = as_u32(pk_f16(acc[0], acc[1]));
  hv.y = as_u32(pk_f16(acc[2], acc[3]));
  *(uint2*)(hQ + ((long)(bh * 8 + kc)) * (N_ / 2) + cdw) = hv;

  const float ap = a[h * 16 + kc], ac = a[h * 16 + 8 + kc];
  float lpv[4], lcv[4];
#pragma unroll
  for (int r = 0; r < 4; ++r) {
    float x = acc[r] * ap, y = acc[r] * ac;
#pragma unroll
    for (int s = 1; s < 8; s <<= 1) {
      x += __shfl_xor(x, s);
      y += __shfl_xor(y, s);
    }
    lpv[r] = x; lcv[r] = y;
  }
  if (kc == 0) {
    float4 l0 = {lpv[0], lpv[1], lpv[2], lpv[3]};
    *(float4*)(lpT + (long)bh * N_ + n0) = l0;
    uint2 q1, q2;
    q1.x = as_u32(pk_f16(__expf(lcv[0]) * SC6, __expf(lcv[1]) * SC6));
    q1.y = as_u32(pk_f16(__expf(lcv[2]) * SC6, __expf(lcv[3]) * SC6));
    q2.x = as_u32(pk_f16(__expf(0.2f * lcv[0]) * SC6, __expf(0.2f * lcv[1]) * SC6));
    q2.y = as_u32(pk_f16(__expf(0.2f * lcv[2]) * SC6, __expf(0.2f * lcv[3]) * SC6));
    // interleave: chunk(16 pairs)=32dw: [q1 quad0|q2 quad0|...|q1 quad3|q2 quad3]
    const int addr = bh * 2048 + (cdw >> 4) * 32 + ((cdw >> 2) & 3) * 8;
    const int off  = cdw & 3;            // 0 or 2
    *(uint2*)(qI + addr + off)     = q1;
    *(uint2*)(qI + addr + 4 + off) = q2;
  }
}

__global__ __launch_bounds__(512) void attn_kernel(
    const float* __restrict__ adj, const unsigned* __restrict__ hQ,
    const unsigned* __restrict__ qI, const float* __restrict__ lpT,
    const unsigned* __restrict__ ones, float* __restrict__ pA,
    float* __restrict__ pL, float* __restrict__ adj_out) {
  const int jq   = blockIdx.x & 3;       // j-quarter (512 wide)
  const int rest = blockIdx.x >> 2;
  const int b    = rest >> 6;            // 64 i-tiles (32-row) per batch
  const int i0   = (rest & 63) * 32;
  const int tid  = threadIdx.x;
  const int w    = tid >> 6;             // 0..7; wave = heads w and w+8
  const int lane = tid & 63;

  // Two 16x512 f16 regions; unit D(u,ch,q,m) = u*1024 + ch*64 + q*16 + m
  __shared__ uint4 sA[2048];             // 32 KB

  // Stage strip (f32 -> f16) + adj copy (once per strip now). Loads hoisted.
  {
    const long aoff = (long)(b * N_ + i0) * N_ + jq * 512;
    const float* abase = adj + aoff;
    float* obase = adj_out + aoff;
    float4 fa[4], fb[4];
    int rowv[4], ccv[4];
#pragma unroll
    for (int s = 0; s < 4; ++s) {
      const int D = s * 512 + tid;
      const int u = D >> 10, loc = D & 1023;
      const int mm = loc & 15, qc = loc >> 4;      // qc = ch*4+q
      ccv[s] = (qc >> 2) * 32 + (qc & 3) * 8;
      rowv[s] = u * 16 + mm;
      fa[s] = *(const float4*)(abase + (long)rowv[s] * N_ + ccv[s]);
      fb[s] = *(const float4*)(abase + (long)rowv[s] * N_ + ccv[s] + 4);
    }
#pragma unroll
    for (int s = 0; s < 4; ++s) {
      const int D = s * 512 + tid;
      uint4 uu;
      uu.x = as_u32(pk_f16(fa[s].x, fa[s].y)); uu.y = as_u32(pk_f16(fa[s].z, fa[s].w));
      uu.z = as_u32(pk_f16(fb[s].x, fb[s].y)); uu.w = as_u32(pk_f16(fb[s].z, fb[s].w));
      sA[D] = uu;
      *(float4*)(obase + (long)rowv[s] * N_ + ccv[s])     = fa[s];
      *(float4*)(obase + (long)rowv[s] * N_ + ccv[s] + 4) = fb[s];
    }
  }
  __syncthreads();

  const int m  = lane & 15;              // A row / B col / D col
  const int q  = lane >> 4;              // k-quad
  const int bh0 = b * H_ + w;            // head-group 0
  const int bh1 = bh0 + 8;               // head-group 1

  const float lpa0 = lpT[(long)bh0 * N_ + i0 + m];
  const float lpb0 = lpT[(long)bh0 * N_ + i0 + 16 + m];
  const float lpa1 = lpT[(long)bh1 * N_ + i0 + m];
  const float lpb1 = lpT[(long)bh1 * N_ + i0 + 16 + m];
  const h2 P1a0 = pk_f16(__expf(lpa0) * SC6, __expf(lpa0) * SC6);
  const h2 P2a0 = pk_f16(__expf(0.2f * lpa0) * SC6, __expf(0.2f * lpa0) * SC6);
  const h2 P1b0 = pk_f16(__expf(lpb0) * SC6, __expf(lpb0) * SC6);
  const h2 P2b0 = pk_f16(__expf(0.2f * lpb0) * SC6, __expf(0.2f * lpb0) * SC6);
  const h2 P1a1 = pk_f16(__expf(lpa1) * SC6, __expf(lpa1) * SC6);
  const h2 P2a1 = pk_f16(__expf(0.2f * lpa1) * SC6, __expf(0.2f * lpa1) * SC6);
  const h2 P1b1 = pk_f16(__expf(lpb1) * SC6, __expf(lpb1) * SC6);
  const h2 P2b1 = pk_f16(__expf(0.2f * lpb1) * SC6, __expf(0.2f * lpb1) * SC6);

  const unsigned* qp0 = qI + bh0 * 2048 + jq * 512 + q * 8;
  const unsigned* qp1 = qI + bh1 * 2048 + jq * 512 + q * 8;
  const unsigned* hp0 = (m < 8)
      ? hQ + ((long)(bh0 * 8 + m)) * (N_ / 2) + jq * 256 + q * 4
      : ones + q * 4;
  const unsigned* hp1 = (m < 8)
      ? hQ + ((long)(bh1 * 8 + m)) * (N_ / 2) + jq * 256 + q * 4
      : ones + q * 4;

  v4f acc0a = {0.f, 0.f, 0.f, 0.f}, acc1a = {0.f, 0.f, 0.f, 0.f};
  v4f acc0b = {0.f, 0.f, 0.f, 0.f}, acc1b = {0.f, 0.f, 0.f, 0.f};

  // 2-deep pipelined loads over 16 chunks (qI stride 32 dw, hQ stride 16 dw).
  uint4 q1X0 = *(const uint4*)(qp0),      q2X0 = *(const uint4*)(qp0 + 4),
        hX0  = *(const uint4*)(hp0);
  uint4 q1X1 = *(const uint4*)(qp1),      q2X1 = *(const uint4*)(qp1 + 4),
        hX1  = *(const uint4*)(hp1);
  uint4 q1Y0 = *(const uint4*)(qp0 + 32), q2Y0 = *(const uint4*)(qp0 + 36),
        hY0  = *(const uint4*)(hp0 + 16);
  uint4 q1Y1 = *(const uint4*)(qp1 + 32), q2Y1 = *(const uint4*)(qp1 + 36),
        hY1  = *(const uint4*)(hp1 + 16);

  for (int t2 = 0; t2 < 8; ++t2) {
    const int ch0 = 2 * t2, ch1 = 2 * t2 + 1;
    const int pq0 = ((ch0 + 2) & 15) * 32, ph0 = ((ch0 + 2) & 15) * 16;
    const int pq1 = ((ch1 + 2) & 15) * 32, ph1 = ((ch1 + 2) & 15) * 16;

    // ---- even chunk: compute with X set, prefetch ch0+2
    const uint4 n10 = *(const uint4*)(qp0 + pq0);
    const uint4 n20 = *(const uint4*)(qp0 + pq0 + 4);
    const uint4 nh0 = *(const uint4*)(hp0 + ph0);
    const uint4 n11 = *(const uint4*)(qp1 + pq0);
    const uint4 n21 = *(const uint4*)(qp1 + pq0 + 4);
    const uint4 nh1 = *(const uint4*)(hp1 + ph0);
    {
      const uint4 Av0 = sA[ch0 * 64 + lane];
      const uint4 Av1 = sA[1024 + ch0 * 64 + lane];
      // head-group 0
      {
        const h2 Q1x = as_h2(q1X0.x), Q1y = as_h2(q1X0.y), Q1z = as_h2(q1X0.z), Q1w = as_h2(q1X0.w);
        const h2 Q2x = as_h2(q2X0.x), Q2y = as_h2(q2X0.y), Q2z = as_h2(q2X0.z), Q2w = as_h2(q2X0.w);
        const v8h bf = __builtin_bit_cast(v8h, hX0);
        const uint4 af0 = {
          as_u32(__builtin_elementwise_max(P1a0 * Q1x, P2a0 * Q2x) * as_h2(Av0.x)),
          as_u32(__builtin_elementwise_max(P1a0 * Q1y, P2a0 * Q2y) * as_h2(Av0.y)),
          as_u32(__builtin_elementwise_max(P1a0 * Q1z, P2a0 * Q2z) * as_h2(Av0.z)),
          as_u32(__builtin_elementwise_max(P1a0 * Q1w, P2a0 * Q2w) * as_h2(Av0.w))};
        acc0a = __builtin_amdgcn_mfma_f32_16x16x32_f16(
            __builtin_bit_cast(v8h, af0), bf, acc0a, 0, 0, 0);
        const uint4 af1 = {
          as_u32(__builtin_elementwise_max(P1b0 * Q1x, P2b0 * Q2x) * as_h2(Av1.x)),
          as_u32(__builtin_elementwise_max(P1b0 * Q1y, P2b0 * Q2y) * as_h2(Av1.y)),
          as_u32(__builtin_elementwise_max(P1b0 * Q1z, P2b0 * Q2z) * as_h2(Av1.z)),
          as_u32(__builtin_elementwise_max(P1b0 * Q1w, P2b0 * Q2w) * as_h2(Av1.w))};
        acc1a = __builtin_amdgcn_mfma_f32_16x16x32_f16(
            __builtin_bit_cast(v8h, af1), bf, acc1a, 0, 0, 0);
      }
      // head-group 1
      {
        const h2 Q1x = as_h2(q1X1.x), Q1y = as_h2(q1X1.y), Q1z = as_h2(q1X1.z), Q1w = as_h2(q1X1.w);
        const h2 Q2x = as_h2(q2X1.x), Q2y = as_h2(q2X1.y), Q2z = as_h2(q2X1.z), Q2w = as_h2(q2X1.w);
        const v8h bf = __builtin_bit_cast(v8h, hX1);
        const uint4 af0 = {
          as_u32(__builtin_elementwise_max(P1a1 * Q1x, P2a1 * Q2x) * as_h2(Av0.x)),
          as_u32(__builtin_elementwise_max(P1a1 * Q1y, P2a1 * Q2y) * as_h2(Av0.y)),
          as_u32(__builtin_elementwise_max(P1a1 * Q1z, P2a1 * Q2z) * as_h2(Av0.z)),
          as_u32(__builtin_elementwise_max(P1a1 * Q1w, P2a1 * Q2w) * as_h2(Av0.w))};
        acc0b = __builtin_amdgcn_mfma_f32_16x16x32_f16(
            __builtin_bit_cast(v8h, af0), bf, acc0b, 0, 0, 0);
        const uint4 af1 = {
          as_u32(__builtin_elementwise_max(P1b1 * Q1x, P2b1 * Q2x) * as_h2(Av1.x)),
          as_u32(__builtin_elementwise_max(P1b1 * Q1y, P2b1 * Q2y) * as_h2(Av1.y)),
          as_u32(__builtin_elementwise_max(P1b1 * Q1z, P2b1 * Q2z) * as_h2(Av1.z)),
          as_u32(__builtin_elementwise_max(P1b1 * Q1w, P2b1 * Q2w) * as_h2(Av1.w))};
        acc1b = __builtin_amdgcn_mfma_f32_16x16x32_f16(
            __builtin_bit_cast(v8h, af1), bf, acc1b, 0, 0, 0);
      }
    }
    q1X0 = n10; q2X0 = n20; hX0 = nh0;
    q1X1 = n11; q2X1 = n21; hX1 = nh1;

    // ---- odd chunk: compute with Y set, prefetch ch1+2
    const uint4 m10 = *(const uint4*)(qp0 + pq1);
    const uint4 m20 = *(const uint4*)(qp0 + pq1 + 4);
    const uint4 mh0 = *(const uint4*)(hp0 + ph1);
    const uint4 m11 = *(const uint4*)(qp1 + pq1);
    const uint4 m21 = *(const uint4*)(qp1 + pq1 + 4);
    const uint4 mh1 = *(const uint4*)(hp1 + ph1);
    {
      const uint4 Av0 = sA[ch1 * 64 + lane];
      const uint4 Av1 = sA[1024 + ch1 * 64 + lane];
      {
        const h2 Q1x = as_h2(q1Y0.x), Q1y = as_h2(q1Y0.y), Q1z = as_h2(q1Y0.z), Q1w = as_h2(q1Y0.w);
        const h2 Q2x = as_h2(q2Y0.x), Q2y = as_h2(q2Y0.y), Q2z = as_h2(q2Y0.z), Q2w = as_h2(q2Y0.w);
        const v8h bf = __builtin_bit_cast(v8h, hY0);
        const uint4 af0 = {
          as_u32(__builtin_elementwise_max(P1a0 * Q1x, P2a0 * Q2x) * as_h2(Av0.x)),
          as_u32(__builtin_elementwise_max(P1a0 * Q1y, P2a0 * Q2y) * as_h2(Av0.y)),
          as_u32(__builtin_elementwise_max(P1a0 * Q1z, P2a0 * Q2z) * as_h2(Av0.z)),
          as_u32(__builtin_elementwise_max(P1a0 * Q1w, P2a0 * Q2w) * as_h2(Av0.w))};
        acc0a = __builtin_amdgcn_mfma_f32_16x16x32_f16(
            __builtin_bit_cast(v8h, af0), bf, acc0a, 0, 0, 0);
        const uint4 af1 = {
          as_u32(__builtin_elementwise_max(P1b0 * Q1x, P2b0 * Q2x) * as_h2(Av1.x)),
          as_u32(__builtin_elementwise_max(P1b0 * Q1y, P2b0 * Q2y) * as_h2(Av1.y)),
          as_u32(__builtin_elementwise_max(P1b0 * Q1z, P2b0 * Q2z) * as_h2(Av1.z)),
          as_u32(__builtin_elementwise_max(P1b0 * Q1w, P2b0 * Q2w) * as_h2(Av1.w))};
        acc1a = __builtin_amdgcn_mfma_f32_16x16x32_f16(
            __builtin_bit_cast(v8h, af1), bf, acc1a, 0, 0, 0);
      }
      {
        const h2 Q1x = as_h2(q1Y1.x), Q1y = as_h2(q1Y1.y), Q1z = as_h2(q1Y1.z), Q1w = as_h2(q1Y1.w);
        const h2 Q2x = as_h2(q2Y1.x), Q2y = as_h2(q2Y1.y), Q2z = as_h2(q2Y1.z), Q2w = as_h2(q2Y1.w);
        const v8h bf = __builtin_bit_cast(v8h, hY1);
        const uint4 af0 = {
          as_u32(__builtin_elementwise_max(P1a1 * Q1x, P2a1 * Q2x) * as_h2(Av0.x)),
          as_u32(__builtin_elementwise_max(P1a1 * Q1y, P2a1 * Q2y) * as_h2(Av0.y)),
          as_u32(__builtin_elementwise_max(P1a1 * Q1z, P2a1 * Q2z) * as_h2(Av0.z)),
          as_u32(__builtin_elementwise_max(P1a1 * Q1w, P2a1 * Q2w) * as_h2(Av0.w))};
        acc0b = __builtin_amdgcn_mfma_f32_16x16x32_f16(
            __builtin_bit_cast(v8h, af0), bf, acc0b, 0, 0, 0);
        const uint4 af1 = {
          as_u32(__builtin_elementwise_max(P1b1 * Q1x, P2b1 * Q2x) * as_h2(Av1.x)),
          as_u32(__builtin_elementwise_max(P1b1 * Q1y, P2b1 * Q2y) * as_h2(Av1.y)),
          as_u32(__builtin_elementwise_max(P1b1 * Q1z, P2b1 * Q2z) * as_h2(Av1.z)),
          as_u32(__builtin_elementwise_max(P1b1 * Q1w, P2b1 * Q2w) * as_h2(Av1.w))};
        acc1b = __builtin_amdgcn_mfma_f32_16x16x32_f16(
            __builtin_bit_cast(v8h, af1), bf, acc1b, 0, 0, 0);
      }
    }
    q1Y0 = m10; q2Y0 = m20; hY0 = mh0;
    q1Y1 = m11; q2Y1 = m21; hY1 = mh1;
  }

  // D: col = lane&15, row = q*4 + reg. Write partials (no division).
#pragma unroll
  for (int g = 0; g < 2; ++g) {          // head-group
    const int hw = g * 8 + w;
#pragma unroll
    for (int u = 0; u < 2; ++u) {        // i-tile
      const v4f av = g ? (u ? acc1b : acc0b) : (u ? acc1a : acc0a);
#pragma unroll
      for (int r = 0; r < 4; ++r) {
        const int gidx = (b * N_ + i0 + u * 16 + q * 4 + r) * H_ + hw;
        if (m < 8)  pA[jq * 524288 + (long)gidx * 8 + m] = av[r];
        if (m == 8) pL[jq * 65536 + gidx] = av[r];
      }
    }
  }
}

__global__ __launch_bounds__(512) void combine_kernel(
    const float* __restrict__ pA, const float* __restrict__ pL,
    float* __restrict__ out) {
  const int g = blockIdx.x * 512 + threadIdx.x;    // = ((b*N+i)*16+h)*8+k
  const int gl = g >> 3;
  const float s = pL[gl] + pL[gl + 65536] + pL[gl + 131072] + pL[gl + 196608];
  const float v = pA[g] + pA[g + 524288] + pA[g + 1048576] + pA[g + 1572864];
  out[g] = v / s;
}

extern "C" void kernel_launch(void* const* d_in, const int* in_sizes, int n_in,
                              void* d_out, int out_size, void* d_ws, size_t ws_size,
                              hipStream_t stream) {
  const float* nf   = (const float*)d_in[0];
  const float* adj  = (const float*)d_in[1];
  const float* W    = (const float*)d_in[2];
  const float* bias = (const float*)d_in[3];
  const float* a    = (const float*)d_in[4];

  float* out     = (float*)d_out;
  float* adj_out = out + (long)B_ * N_ * H_ * 8;    // 524288 offset

  unsigned* ws   = (unsigned*)d_ws;
  unsigned* hQ   = ws;                       // 262144 dw
  unsigned* qI   = ws + 262144;              // 65536 dw
  float*    lpT  = (float*)(ws + 327680);    // 65536 floats
  unsigned* ones = ws + 393216;              // 512 dw
  float*    pA   = (float*)(ws + 393728);    // 4 * 524288 floats
  float*    pL   = (float*)(ws + 2490880);   // 4 * 65536 floats

  hipLaunchKernelGGL(proj_kernel, dim3(B_ * N_ / 4), dim3(128), 0, stream,
                     nf, W, bias, a, hQ, qI, lpT, ones);
  hipLaunchKernelGGL(attn_kernel, dim3(B_ * (N_ / 32) * 4), dim3(512), 0,
                     stream, adj, hQ, qI, lpT, ones, pA, pL, adj_out);
  hipLaunchKernelGGL(combine_kernel, dim3(1024), dim3(512), 0, stream,
                     pA, pL, out);
}

// Round 14
// 122.986 us; speedup vs baseline: 1.3010x; 1.0660x over previous
//
#include <hip/hip_runtime.h>
#include <hip/hip_bf16.h>

// GAT layer: B=2, N=2048, C_IN=128, H=16, c=8.
// E(i,j) = exp(lrelu(lp_i+lc_j))*2^-12 = max(P1_i*Q1_j, P2_i*Q2_j)*adj  (f16).
// Aggregation: mfma_f32_16x16x32_f16; B-operand = [h feats | ones buffer].
// Round 14: q1/q2 streams staged into LDS (32 KB, LLC-hot, broadcast reads)
// -> j-loop global loads drop 6/chunk -> 2/chunk (hQ, 4-deep prefetch array);
// the per-chunk dependent-load latency chain was the r11-r13 limiter.
// d_out = [out: B*N*128][adj copy: B*N*N]

#define B_   2
#define N_   2048
#define CIN_ 128
#define H_   16

typedef _Float16 h2  __attribute__((ext_vector_type(2)));
typedef _Float16 v8h __attribute__((ext_vector_type(8)));
typedef float    v4f __attribute__((ext_vector_type(4)));

#define SC6 0.015625f   // 2^-6

__device__ inline h2 pk_f16(float a, float b) {
  return __builtin_bit_cast(h2, __builtin_amdgcn_cvt_pkrtz(a, b));
}
__device__ inline unsigned as_u32(h2 v) { return __builtin_bit_cast(unsigned, v); }
__device__ inline h2 as_h2(unsigned u) { return __builtin_bit_cast(h2, u); }

__global__ __launch_bounds__(128) void proj_kernel(
    const float* __restrict__ nf, const float* __restrict__ W,
    const float* __restrict__ bias, const float* __restrict__ a,
    unsigned* __restrict__ hQ, unsigned* __restrict__ qI,
    float* __restrict__ lpT, unsigned* __restrict__ ones) {
  const int row0 = blockIdx.x * 4;       // 4 consecutive rows (same batch)
  const int t    = threadIdx.x;          // output column 0..127
  if (blockIdx.x == 0) {                 // ones-buffer for B-operand cols 8..15
    ones[t] = 0x3C003C00u; ones[t + 128] = 0x3C003C00u;
    ones[t + 256] = 0x3C003C00u; ones[t + 384] = 0x3C003C00u;
  }
  __shared__ float sNf[4][CIN_];
  ((float4*)&sNf[0][0])[t] = ((const float4*)(nf + (long)row0 * CIN_))[t];
  __syncthreads();
  float acc[4];
  const float bv = bias[t];
#pragma unroll
  for (int r = 0; r < 4; ++r) acc[r] = bv;
#pragma unroll 8
  for (int k = 0; k < CIN_; ++k) {
    const float w = W[k * 128 + t];
#pragma unroll
    for (int r = 0; r < 4; ++r) acc[r] = fmaf(sNf[r][k], w, acc[r]);
  }
  const int h = t >> 3, kc = t & 7;
  const int b = row0 >> 11, n0 = row0 & (N_ - 1);
  const int bh = b * H_ + h;
  const int cdw = n0 >> 1;               // j-pair dword index (2-aligned)
  uint2 hv;
  hv.x = as_u32(pk_f16(acc[0], acc[1]));
  hv.y = as_u32(pk_f16(acc[2], acc[3]));
  *(uint2*)(hQ + ((long)(bh * 8 + kc)) * (N_ / 2) + cdw) = hv;

  const float ap = a[h * 16 + kc], ac = a[h * 16 + 8 + kc];
  float lpv[4], lcv[4];
#pragma unroll
  for (int r = 0; r < 4; ++r) {
    float x = acc[r] * ap, y = acc[r] * ac;
#pragma unroll
    for (int s = 1; s < 8; s <<= 1) {
      x += __shfl_xor(x, s);
      y += __shfl_xor(y, s);
    }
    lpv[r] = x; lcv[r] = y;
  }
  if (kc == 0) {
    float4 l0 = {lpv[0], lpv[1], lpv[2], lpv[3]};
    *(float4*)(lpT + (long)bh * N_ + n0) = l0;
    uint2 q1, q2;
    q1.x = as_u32(pk_f16(__expf(lcv[0]) * SC6, __expf(lcv[1]) * SC6));
    q1.y = as_u32(pk_f16(__expf(lcv[2]) * SC6, __expf(lcv[3]) * SC6));
    q2.x = as_u32(pk_f16(__expf(0.2f * lcv[0]) * SC6, __expf(0.2f * lcv[1]) * SC6));
    q2.y = as_u32(pk_f16(__expf(0.2f * lcv[2]) * SC6, __expf(0.2f * lcv[3]) * SC6));
    // interleave: chunk(16 pairs)=32dw: [q1 quad0|q2 quad0|...|q1 quad3|q2 quad3]
    const int addr = bh * 2048 + (cdw >> 4) * 32 + ((cdw >> 2) & 3) * 8;
    const int off  = cdw & 3;            // 0 or 2
    *(uint2*)(qI + addr + off)     = q1;
    *(uint2*)(qI + addr + 4 + off) = q2;
  }
}

__global__ __launch_bounds__(512) void attn_kernel(
    const float* __restrict__ adj, const unsigned* __restrict__ hQ,
    const unsigned* __restrict__ qI, const float* __restrict__ lpT,
    const unsigned* __restrict__ ones, float* __restrict__ pA,
    float* __restrict__ pL, float* __restrict__ adj_out) {
  const int jq   = blockIdx.x & 3;       // j-quarter (512 wide)
  const int rest = blockIdx.x >> 2;
  const int b    = rest >> 6;            // 64 i-tiles (32-row) per batch
  const int i0   = (rest & 63) * 32;
  const int tid  = threadIdx.x;
  const int w    = tid >> 6;             // 0..7; wave = heads w and w+8
  const int lane = tid & 63;

  __shared__ uint4    sA[2048];          // 32 KB: adj f16, D = u*1024+ch*64+q*16+m
  __shared__ unsigned sQ[8192];          // 32 KB: q1/q2 for 16 heads (qI layout)

  // ---- Stage sQ: thread t copies 16 dw of head (t>>5)'s j-quarter.
  {
    const int head = tid >> 5;
    const int off  = (tid & 31) * 16;
    const uint4* src = (const uint4*)(qI + (b * H_ + head) * 2048 + jq * 512 + off);
    uint4* dst = (uint4*)(sQ + head * 512 + off);
    dst[0] = src[0]; dst[1] = src[1]; dst[2] = src[2]; dst[3] = src[3];
  }
  // ---- Stage adjacency (f32 -> f16) + fused copy; loads hoisted.
  {
    const long aoff = (long)(b * N_ + i0) * N_ + jq * 512;
    const float* abase = adj + aoff;
    float* obase = adj_out + aoff;
    float4 fa[4], fb[4];
    int rowv[4], ccv[4];
#pragma unroll
    for (int s = 0; s < 4; ++s) {
      const int D = s * 512 + tid;
      const int u = D >> 10, loc = D & 1023;
      const int mm = loc & 15, qc = loc >> 4;
      ccv[s] = (qc >> 2) * 32 + (qc & 3) * 8;
      rowv[s] = u * 16 + mm;
      fa[s] = *(const float4*)(abase + (long)rowv[s] * N_ + ccv[s]);
      fb[s] = *(const float4*)(abase + (long)rowv[s] * N_ + ccv[s] + 4);
    }
#pragma unroll
    for (int s = 0; s < 4; ++s) {
      const int D = s * 512 + tid;
      uint4 uu;
      uu.x = as_u32(pk_f16(fa[s].x, fa[s].y)); uu.y = as_u32(pk_f16(fa[s].z, fa[s].w));
      uu.z = as_u32(pk_f16(fb[s].x, fb[s].y)); uu.w = as_u32(pk_f16(fb[s].z, fb[s].w));
      sA[D] = uu;
      *(float4*)(obase + (long)rowv[s] * N_ + ccv[s])     = fa[s];
      *(float4*)(obase + (long)rowv[s] * N_ + ccv[s] + 4) = fb[s];
    }
  }
  __syncthreads();

  const int m  = lane & 15;              // A row / B col / D col
  const int q  = lane >> 4;              // k-quad
  const int bh0 = b * H_ + w;            // head-group 0
  const int bh1 = bh0 + 8;               // head-group 1

  const float lpa0 = lpT[(long)bh0 * N_ + i0 + m];
  const float lpb0 = lpT[(long)bh0 * N_ + i0 + 16 + m];
  const float lpa1 = lpT[(long)bh1 * N_ + i0 + m];
  const float lpb1 = lpT[(long)bh1 * N_ + i0 + 16 + m];
  const h2 P1a0 = pk_f16(__expf(lpa0) * SC6, __expf(lpa0) * SC6);
  const h2 P2a0 = pk_f16(__expf(0.2f * lpa0) * SC6, __expf(0.2f * lpa0) * SC6);
  const h2 P1b0 = pk_f16(__expf(lpb0) * SC6, __expf(lpb0) * SC6);
  const h2 P2b0 = pk_f16(__expf(0.2f * lpb0) * SC6, __expf(0.2f * lpb0) * SC6);
  const h2 P1a1 = pk_f16(__expf(lpa1) * SC6, __expf(lpa1) * SC6);
  const h2 P2a1 = pk_f16(__expf(0.2f * lpa1) * SC6, __expf(0.2f * lpa1) * SC6);
  const h2 P1b1 = pk_f16(__expf(lpb1) * SC6, __expf(lpb1) * SC6);
  const h2 P2b1 = pk_f16(__expf(0.2f * lpb1) * SC6, __expf(0.2f * lpb1) * SC6);

  const unsigned* sq0 = sQ + w * 512 + q * 8;
  const unsigned* sq1 = sQ + (w + 8) * 512 + q * 8;
  const unsigned* hp0 = (m < 8)
      ? hQ + ((long)(bh0 * 8 + m)) * (N_ / 2) + jq * 256 + q * 4
      : ones + q * 4;
  const unsigned* hp1 = (m < 8)
      ? hQ + ((long)(bh1 * 8 + m)) * (N_ / 2) + jq * 256 + q * 4
      : ones + q * 4;

  v4f acc0a = {0.f, 0.f, 0.f, 0.f}, acc1a = {0.f, 0.f, 0.f, 0.f};
  v4f acc0b = {0.f, 0.f, 0.f, 0.f}, acc1b = {0.f, 0.f, 0.f, 0.f};

  // 4-deep prefetch of the only remaining global stream (hQ, 2 head-groups).
  uint4 h0[4], h1[4];
#pragma unroll
  for (int d = 0; d < 4; ++d) {
    h0[d] = *(const uint4*)(hp0 + d * 16);
    h1[d] = *(const uint4*)(hp1 + d * 16);
  }

  for (int t4 = 0; t4 < 4; ++t4) {
#pragma unroll
    for (int s = 0; s < 4; ++s) {
      const int ch = t4 * 4 + s;
      const int pf = ((ch + 4) & 15) * 16;
      const uint4 n0 = *(const uint4*)(hp0 + pf);
      const uint4 n1 = *(const uint4*)(hp1 + pf);

      const uint4 q1c0 = *(const uint4*)(sq0 + ch * 32);
      const uint4 q2c0 = *(const uint4*)(sq0 + ch * 32 + 4);
      const uint4 q1c1 = *(const uint4*)(sq1 + ch * 32);
      const uint4 q2c1 = *(const uint4*)(sq1 + ch * 32 + 4);
      const uint4 Av0 = sA[ch * 64 + lane];
      const uint4 Av1 = sA[1024 + ch * 64 + lane];

      // head-group 0
      {
        const h2 Q1x = as_h2(q1c0.x), Q1y = as_h2(q1c0.y), Q1z = as_h2(q1c0.z), Q1w = as_h2(q1c0.w);
        const h2 Q2x = as_h2(q2c0.x), Q2y = as_h2(q2c0.y), Q2z = as_h2(q2c0.z), Q2w = as_h2(q2c0.w);
        const v8h bf = __builtin_bit_cast(v8h, h0[s]);
        const uint4 af0 = {
          as_u32(__builtin_elementwise_max(P1a0 * Q1x, P2a0 * Q2x) * as_h2(Av0.x)),
          as_u32(__builtin_elementwise_max(P1a0 * Q1y, P2a0 * Q2y) * as_h2(Av0.y)),
          as_u32(__builtin_elementwise_max(P1a0 * Q1z, P2a0 * Q2z) * as_h2(Av0.z)),
          as_u32(__builtin_elementwise_max(P1a0 * Q1w, P2a0 * Q2w) * as_h2(Av0.w))};
        acc0a = __builtin_amdgcn_mfma_f32_16x16x32_f16(
            __builtin_bit_cast(v8h, af0), bf, acc0a, 0, 0, 0);
        const uint4 af1 = {
          as_u32(__builtin_elementwise_max(P1b0 * Q1x, P2b0 * Q2x) * as_h2(Av1.x)),
          as_u32(__builtin_elementwise_max(P1b0 * Q1y, P2b0 * Q2y) * as_h2(Av1.y)),
          as_u32(__builtin_elementwise_max(P1b0 * Q1z, P2b0 * Q2z) * as_h2(Av1.z)),
          as_u32(__builtin_elementwise_max(P1b0 * Q1w, P2b0 * Q2w) * as_h2(Av1.w))};
        acc1a = __builtin_amdgcn_mfma_f32_16x16x32_f16(
            __builtin_bit_cast(v8h, af1), bf, acc1a, 0, 0, 0);
      }
      // head-group 1
      {
        const h2 Q1x = as_h2(q1c1.x), Q1y = as_h2(q1c1.y), Q1z = as_h2(q1c1.z), Q1w = as_h2(q1c1.w);
        const h2 Q2x = as_h2(q2c1.x), Q2y = as_h2(q2c1.y), Q2z = as_h2(q2c1.z), Q2w = as_h2(q2c1.w);
        const v8h bf = __builtin_bit_cast(v8h, h1[s]);
        const uint4 af0 = {
          as_u32(__builtin_elementwise_max(P1a1 * Q1x, P2a1 * Q2x) * as_h2(Av0.x)),
          as_u32(__builtin_elementwise_max(P1a1 * Q1y, P2a1 * Q2y) * as_h2(Av0.y)),
          as_u32(__builtin_elementwise_max(P1a1 * Q1z, P2a1 * Q2z) * as_h2(Av0.z)),
          as_u32(__builtin_elementwise_max(P1a1 * Q1w, P2a1 * Q2w) * as_h2(Av0.w))};
        acc0b = __builtin_amdgcn_mfma_f32_16x16x32_f16(
            __builtin_bit_cast(v8h, af0), bf, acc0b, 0, 0, 0);
        const uint4 af1 = {
          as_u32(__builtin_elementwise_max(P1b1 * Q1x, P2b1 * Q2x) * as_h2(Av1.x)),
          as_u32(__builtin_elementwise_max(P1b1 * Q1y, P2b1 * Q2y) * as_h2(Av1.y)),
          as_u32(__builtin_elementwise_max(P1b1 * Q1z, P2b1 * Q2z) * as_h2(Av1.z)),
          as_u32(__builtin_elementwise_max(P1b1 * Q1w, P2b1 * Q2w) * as_h2(Av1.w))};
        acc1b = __builtin_amdgcn_mfma_f32_16x16x32_f16(
            __builtin_bit_cast(v8h, af1), bf, acc1b, 0, 0, 0);
      }
      h0[s] = n0; h1[s] = n1;
    }
  }

  // D: col = lane&15, row = q*4 + reg. Write partials (no division).
#pragma unroll
  for (int g = 0; g < 2; ++g) {          // head-group
    const int hw = g * 8 + w;
#pragma unroll
    for (int u = 0; u < 2; ++u) {        // i-tile
      const v4f av = g ? (u ? acc1b : acc0b) : (u ? acc1a : acc0a);
#pragma unroll
      for (int r = 0; r < 4; ++r) {
        const int gidx = (b * N_ + i0 + u * 16 + q * 4 + r) * H_ + hw;
        if (m < 8)  pA[jq * 524288 + (long)gidx * 8 + m] = av[r];
        if (m == 8) pL[jq * 65536 + gidx] = av[r];
      }
    }
  }
}

__global__ __launch_bounds__(512) void combine_kernel(
    const float* __restrict__ pA, const float* __restrict__ pL,
    float* __restrict__ out) {
  const int g = blockIdx.x * 512 + threadIdx.x;    // = ((b*N+i)*16+h)*8+k
  const int gl = g >> 3;
  const float s = pL[gl] + pL[gl + 65536] + pL[gl + 131072] + pL[gl + 196608];
  const float v = pA[g] + pA[g + 524288] + pA[g + 1048576] + pA[g + 1572864];
  out[g] = v / s;
}

extern "C" void kernel_launch(void* const* d_in, const int* in_sizes, int n_in,
                              void* d_out, int out_size, void* d_ws, size_t ws_size,
                              hipStream_t stream) {
  const float* nf   = (const float*)d_in[0];
  const float* adj  = (const float*)d_in[1];
  const float* W    = (const float*)d_in[2];
  const float* bias = (const float*)d_in[3];
  const float* a    = (const float*)d_in[4];

  float* out     = (float*)d_out;
  float* adj_out = out + (long)B_ * N_ * H_ * 8;    // 524288 offset

  unsigned* ws   = (unsigned*)d_ws;
  unsigned* hQ   = ws;                       // 262144 dw
  unsigned* qI   = ws + 262144;              // 65536 dw
  float*    lpT  = (float*)(ws + 327680);    // 65536 floats
  unsigned* ones = ws + 393216;              // 512 dw
  float*    pA   = (float*)(ws + 393728);    // 4 * 524288 floats
  float*    pL   = (float*)(ws + 2490880);   // 4 * 65536 floats

  hipLaunchKernelGGL(proj_kernel, dim3(B_ * N_ / 4), dim3(128), 0, stream,
                     nf, W, bias, a, hQ, qI, lpT, ones);
  hipLaunchKernelGGL(attn_kernel, dim3(B_ * (N_ / 32) * 4), dim3(512), 0,
                     stream, adj, hQ, qI, lpT, ones, pA, pL, adj_out);
  hipLaunchKernelGGL(combine_kernel, dim3(1024), dim3(512), 0, stream,
                     pA, pL, out);
}